// Round 2
// baseline (94.468 us; speedup 1.0000x reference)
//
#include <hip/hip_runtime.h>
#include <math.h>

#define CI 64
#define CO 128
#define CX 69
#define LPIX 1024   // 32*32

// ---------------------------------------------------------------------------
// Kernel A: conv3x3 (zero-pad) + shape-distance + saf + q (1x1 conv reduce)
// grid: 256 blocks (16 batches x 16 row-stripes of 2 rows), 512 threads.
// Wave = 64 pixels (2 rows x 32 cols); each wave owns 16 out-channels in
// acc[16]. Weights/bias/shape-kernels are wave-uniform -> scalar loads
// (SGPR broadcast operand of v_fmac), zero LDS traffic for weights.
// ---------------------------------------------------------------------------
__launch_bounds__(512)
__global__ void convA(const float* __restrict__ xg,
                      const float* __restrict__ cwg,
                      const float* __restrict__ cbg,
                      const float* __restrict__ w2g,
                      const float* __restrict__ b2g,
                      const float* __restrict__ skg,
                      float* __restrict__ outg,
                      float* __restrict__ qg) {
  __shared__ float lds_x[64 * 144];    // [ci][4 rows r0-1..r0+2][36 cols], zero-pad
  __shared__ float lds_sx[5 * 144];    // [c][4 rows][36 cols], edge-clamped
  __shared__ float qred[8 * 64];

  const int tid = threadIdx.x;
  const int b  = blockIdx.x >> 4;
  const int r0 = (blockIdx.x & 15) * 2;

  const float* xb = xg + (size_t)b * CX * LPIX;
  const float* xs = xb + CI * LPIX;

  // stage conv input rows (zero padding), col slot j holds col j-1
  for (int idx = tid; idx < 64 * 144; idx += 512) {
    int ci = idx / 144, rem = idx - ci * 144;
    int s = rem / 36, j = rem - s * 36;
    int hh = r0 - 1 + s, col = j - 1;
    float v = 0.f;
    if ((unsigned)hh < 32u && (unsigned)col < 32u)
      v = xb[ci * LPIX + hh * 32 + col];
    lds_x[idx] = v;
  }
  // stage shape rows (edge clamp)
  for (int idx = tid; idx < 5 * 144; idx += 512) {
    int c = idx / 144, rem = idx - c * 144;
    int s = rem / 36, j = rem - s * 36;
    int hh = r0 - 1 + s; hh = hh < 0 ? 0 : (hh > 31 ? 31 : hh);
    int col = j - 1;     col = col < 0 ? 0 : (col > 31 ? 31 : col);
    lds_sx[idx] = xs[c * LPIX + hh * 32 + col];
  }
  __syncthreads();

  const int wv  = __builtin_amdgcn_readfirstlane(tid >> 6);  // wave id 0..7
  const int co0 = wv * 16;
  const int lane = tid & 63;
  const int pr = lane >> 5, wc = lane & 31;
  const int xbase = pr * 36 + wc;   // lane's base element offset within a row-group

  float acc[16];
  #pragma unroll
  for (int cc = 0; cc < 16; ++cc) acc[cc] = cbg[co0 + cc];   // scalar loads

  // main conv loop: per ci, 9 ds_read_b32 (immediate offsets) + 144 v_fmac
  // with SGPR weight operands.
  for (int ci = 0; ci < 64; ++ci) {
    float xv[9];
    #pragma unroll
    for (int s = 0; s < 3; ++s)
      #pragma unroll
      for (int dc = 0; dc < 3; ++dc)
        xv[s * 3 + dc] = lds_x[ci * 144 + s * 36 + dc + xbase];
    const float* wp0 = cwg + (size_t)co0 * 576 + ci * 9;     // wave-uniform
    #pragma unroll
    for (int cc = 0; cc < 16; ++cc) {
      const float* wp = wp0 + cc * 576;
      #pragma unroll
      for (int t = 0; t < 9; ++t)
        acc[cc] = fmaf(xv[t], wp[t], acc[cc]);
    }
  }

  // shape windows into registers (center-relative for channels 0,1)
  float swv[45];
  {
    const float c0 = lds_sx[0 * 144 + 37 + xbase];  // center tap (pr+1, wc+1)
    const float c1 = lds_sx[1 * 144 + 37 + xbase];
    #pragma unroll
    for (int c = 0; c < 5; ++c) {
      float ctr = (c == 0) ? c0 : ((c == 1) ? c1 : 0.f);
      #pragma unroll
      for (int s = 0; s < 3; ++s)
        #pragma unroll
        for (int dc = 0; dc < 3; ++dc)
          swv[c * 9 + s * 3 + dc] = lds_sx[c * 144 + s * 36 + dc + xbase] - ctr;
    }
  }

  // sd + saf + q partial
  float qp = 0.f;
  float* outb = outg + ((size_t)b * 133 + co0) * LPIX + (r0 + pr) * 32 + wc;
  #pragma unroll
  for (int cc = 0; cc < 16; ++cc) {
    const float* kp = skg + (co0 + cc) * 45;                 // wave-uniform
    float s = 0.f;
    #pragma unroll
    for (int j = 0; j < 45; ++j) s += fabsf(swv[j] - kp[j]);
    float v = acc[cc] * __builtin_amdgcn_rcpf(s + 1.0f);
    v = v > 0.f ? v : 0.f;
    outb[(size_t)cc * LPIX] = v;
    qp = fmaf(v, w2g[co0 + cc], qp);
  }

  // cross-wave q reduction (each wave holds a different co group)
  qred[wv * 64 + lane] = qp;
  __syncthreads();
  if (tid < 64) {
    float q = 0.f;
    #pragma unroll
    for (int w8 = 0; w8 < 8; ++w8) q += qred[w8 * 64 + tid];
    q = (q + b2g[0]) * 0.08838834764831845f;  // 1/sqrt(128)
    qg[(size_t)b * LPIX + (r0 + (tid >> 5)) * 32 + (tid & 31)] = q;
  }
}

// ---------------------------------------------------------------------------
// Kernel B: 3x3 zero-padded softmax of q + weighted window stats
// grid: 256 blocks x 64 threads (one wave per block, all CUs covered)
// ---------------------------------------------------------------------------
__launch_bounds__(64)
__global__ void statsB(const float* __restrict__ xg,
                       const float* __restrict__ qg,
                       float* __restrict__ outg) {
  const int gid = blockIdx.x * 64 + threadIdx.x;  // 0..16383
  const int b = gid >> 10;
  const int h = (gid >> 5) & 31;
  const int w = gid & 31;

  const float* qb = qg + (size_t)b * LPIX;
  float qv[9];
  float m = -1e30f;
  #pragma unroll
  for (int t = 0; t < 9; ++t) {
    int hh = h + t / 3 - 1, wc = w + t % 3 - 1;
    float v = 0.f;  // zero padding participates in softmax
    if ((unsigned)hh < 32u && (unsigned)wc < 32u) v = qb[hh * 32 + wc];
    qv[t] = v;
    m = fmaxf(m, v);
  }
  float ssum = 0.f;
  #pragma unroll
  for (int t = 0; t < 9; ++t) { qv[t] = expf(qv[t] - m); ssum += qv[t]; }
  const float inv = 1.f / ssum;

  const float* xs = xg + ((size_t)b * CX + CI) * LPIX;
  float um0[9], um1[9];
  float m0 = 0.f, m1 = 0.f, v1a = 0.f, v1b = 0.f, c1 = 0.f;
  #pragma unroll
  for (int t = 0; t < 9; ++t) {
    int hh = h + t / 3 - 1; hh = hh < 0 ? 0 : (hh > 31 ? 31 : hh);  // edge pad
    int wc = w + t % 3 - 1; wc = wc < 0 ? 0 : (wc > 31 ? 31 : wc);
    int off = hh * 32 + wc;
    float quv = qv[t] * inv;
    qv[t] = quv;
    float a0 = xs[off];
    float a1 = xs[LPIX + off];
    float b0 = xs[2 * LPIX + off];
    float b1 = xs[3 * LPIX + off];
    float cc = xs[4 * LPIX + off];
    um0[t] = a0; um1[t] = a1;
    m0 = fmaf(a0, quv, m0);
    m1 = fmaf(a1, quv, m1);
    v1a = fmaf(b0, quv, v1a);
    v1b = fmaf(b1, quv, v1b);
    c1 = fmaf(cc, quv, c1);
  }
  float var0 = v1a, var1 = v1b, cov = c1;
  #pragma unroll
  for (int t = 0; t < 9; ++t) {
    float d0 = um0[t] - m0, d1 = um1[t] - m1;
    var0 = fmaf(d0 * d0, qv[t], var0);
    var1 = fmaf(d1 * d1, qv[t], var1);
    cov  = fmaf(d0 * d1, qv[t], cov);
  }
  float* ob = outg + ((size_t)b * 133 + 128) * LPIX + h * 32 + w;
  ob[0 * LPIX] = m0;
  ob[1 * LPIX] = m1;
  ob[2 * LPIX] = var0;
  ob[3 * LPIX] = var1;
  ob[4 * LPIX] = cov;
}

extern "C" void kernel_launch(void* const* d_in, const int* in_sizes, int n_in,
                              void* d_out, int out_size, void* d_ws, size_t ws_size,
                              hipStream_t stream) {
  const float* x  = (const float*)d_in[0];
  const float* cw = (const float*)d_in[1];
  const float* cb = (const float*)d_in[2];
  const float* w2 = (const float*)d_in[3];
  const float* b2 = (const float*)d_in[4];
  const float* sk = (const float*)d_in[5];
  float* out = (float*)d_out;
  float* q   = (float*)d_ws;  // 16*1024 floats = 64 KB scratch for q

  convA<<<dim3(256), dim3(512), 0, stream>>>(x, cw, cb, w2, b2, sk, out, q);
  statsB<<<dim3(256), dim3(64), 0, stream>>>(x, q, out);
}

// Round 3
// 61.553 us; speedup vs baseline: 1.5347x; 1.5347x over previous
//
#include <hip/hip_runtime.h>
#include <math.h>

#define CI 64
#define CO 128
#define CX 69
#define LPIX 1024   // 32*32

// ws layout (floats):
//   [0 : 32768)            q_part[2][16][1024]
//   [32768 : 32768+73728)  w_t[576][128]   (k=ci*9+tap major, co minor)
//   [.. : ..+5760)         sk_t[45][128]
#define QPART_OFF 0
#define WT_OFF    32768
#define SKT_OFF   (32768 + 73728)

// ---------------------------------------------------------------------------
// prep: transpose conv weights and shape kernels for aligned s_load_dwordx8
// ---------------------------------------------------------------------------
__launch_bounds__(256)
__global__ void prep(const float* __restrict__ cwg,
                     const float* __restrict__ skg,
                     float* __restrict__ ws) {
  int i = blockIdx.x * 256 + threadIdx.x;
  if (i < 128 * 576) {
    int co = i / 576, k = i - co * 576;      // k = ci*9+tap
    ws[WT_OFF + k * 128 + co] = cwg[i];
  } else if (i < 128 * 576 + 128 * 45) {
    int j = i - 128 * 576;
    int co = j / 45, t = j - co * 45;
    ws[SKT_OFF + t * 128 + co] = skg[j];
  }
}

// ---------------------------------------------------------------------------
// Kernel A: conv3x3 (zero-pad) + shape-distance + saf + q partial
// grid: 512 blocks = 16 batches x 16 row-stripes x 2 co-halves, 512 threads.
// Wave = 64 pixels (2 rows x 32 cols); each wave owns 8 out-channels.
// Weights via wave-uniform scalar loads from the transposed layout.
// ---------------------------------------------------------------------------
__launch_bounds__(512, 4)
__global__ void convA(const float* __restrict__ xg,
                      const float* __restrict__ cbg,
                      const float* __restrict__ w2g,
                      float* __restrict__ ws,
                      float* __restrict__ outg) {
  __shared__ float lds_x[64 * 144];    // [ci][4 rows r0-1..r0+2][36 cols], zero-pad
  __shared__ float lds_sx[5 * 144];    // [c][4 rows][36 cols], edge-clamped
  __shared__ float qred[8][64];

  const int tid  = threadIdx.x;
  const int blk  = blockIdx.x;
  const int half = blk & 1;
  const int r0   = ((blk >> 1) & 15) * 2;
  const int b    = blk >> 5;

  const float* xb = xg + (size_t)b * CX * LPIX;
  const float* xs = xb + CI * LPIX;

  // stage conv input rows (zero padding), col slot j holds col j-1
  for (int idx = tid; idx < 64 * 144; idx += 512) {
    int ci = idx / 144, rem = idx - ci * 144;
    int s = rem / 36, j = rem - s * 36;
    int hh = r0 - 1 + s, col = j - 1;
    float v = 0.f;
    if ((unsigned)hh < 32u && (unsigned)col < 32u)
      v = xb[ci * LPIX + hh * 32 + col];
    lds_x[idx] = v;
  }
  // stage shape rows (edge clamp)
  for (int idx = tid; idx < 5 * 144; idx += 512) {
    int c = idx / 144, rem = idx - c * 144;
    int s = rem / 36, j = rem - s * 36;
    int hh = r0 - 1 + s; hh = hh < 0 ? 0 : (hh > 31 ? 31 : hh);
    int col = j - 1;     col = col < 0 ? 0 : (col > 31 ? 31 : col);
    lds_sx[idx] = xs[c * LPIX + hh * 32 + col];
  }
  __syncthreads();

  const int wv   = __builtin_amdgcn_readfirstlane(tid >> 6);  // wave 0..7
  const int co0  = half * 64 + wv * 8;
  const int lane = tid & 63;
  const int pr = lane >> 5, wc = lane & 31;
  const int xbase = pr * 36 + wc;

  float acc[8];
  #pragma unroll
  for (int cc = 0; cc < 8; ++cc) acc[cc] = cbg[co0 + cc];

  const float* wt = ws + WT_OFF + co0;   // wave-uniform
  // main conv loop: per ci, 9 ds_read_b32 + 9 s_load_dwordx8 + 72 v_fmac
  for (int ci = 0; ci < 64; ++ci) {
    float xv[9];
    #pragma unroll
    for (int s = 0; s < 3; ++s)
      #pragma unroll
      for (int dc = 0; dc < 3; ++dc)
        xv[s * 3 + dc] = lds_x[ci * 144 + s * 36 + dc + xbase];
    const float* wp = wt + (size_t)ci * 9 * 128;
    #pragma unroll
    for (int t = 0; t < 9; ++t) {
      #pragma unroll
      for (int cc = 0; cc < 8; ++cc)
        acc[cc] = fmaf(xv[t], wp[t * 128 + cc], acc[cc]);
    }
  }

  // shape windows into registers (center-relative for channels 0,1)
  float swv[45];
  {
    const float c0 = lds_sx[0 * 144 + 37 + xbase];
    const float c1 = lds_sx[1 * 144 + 37 + xbase];
    #pragma unroll
    for (int c = 0; c < 5; ++c) {
      float ctr = (c == 0) ? c0 : ((c == 1) ? c1 : 0.f);
      #pragma unroll
      for (int s = 0; s < 3; ++s)
        #pragma unroll
        for (int dc = 0; dc < 3; ++dc)
          swv[c * 9 + s * 3 + dc] = lds_sx[c * 144 + s * 36 + dc + xbase] - ctr;
    }
  }

  // sd: per j one s_load_dwordx8 of sk_t, 8 pure-VALU lanes of work
  float sdv[8];
  #pragma unroll
  for (int cc = 0; cc < 8; ++cc) sdv[cc] = 0.f;
  const float* skt = ws + SKT_OFF + co0;  // wave-uniform
  #pragma unroll
  for (int j = 0; j < 45; ++j) {
    float sv = swv[j];
    #pragma unroll
    for (int cc = 0; cc < 8; ++cc)
      sdv[cc] += fabsf(sv - skt[j * 128 + cc]);
  }

  // saf = relu(conv/(sd+1)); store; q partial
  float qp = 0.f;
  float* outb = outg + ((size_t)b * 133 + co0) * LPIX + (r0 + pr) * 32 + wc;
  #pragma unroll
  for (int cc = 0; cc < 8; ++cc) {
    float v = acc[cc] * __builtin_amdgcn_rcpf(sdv[cc] + 1.0f);
    v = v > 0.f ? v : 0.f;
    outb[(size_t)cc * LPIX] = v;
    qp = fmaf(v, w2g[co0 + cc], qp);
  }

  // cross-wave q reduction (8 waves cover 64 co of this half)
  qred[wv][lane] = qp;
  __syncthreads();
  if (tid < 64) {
    float q = 0.f;
    #pragma unroll
    for (int w8 = 0; w8 < 8; ++w8) q += qred[w8][tid];
    ws[QPART_OFF + half * 16384 + b * LPIX + (r0 + (tid >> 5)) * 32 + (tid & 31)] = q;
  }
}

// ---------------------------------------------------------------------------
// Kernel B: combine q halves, 3x3 zero-padded softmax + weighted window stats
// ---------------------------------------------------------------------------
__launch_bounds__(64)
__global__ void statsB(const float* __restrict__ xg,
                       const float* __restrict__ ws,
                       const float* __restrict__ b2g,
                       float* __restrict__ outg) {
  const int gid = blockIdx.x * 64 + threadIdx.x;  // 0..16383
  const int b = gid >> 10;
  const int h = (gid >> 5) & 31;
  const int w = gid & 31;

  const float b2 = b2g[0];
  const float* q0 = ws + QPART_OFF + (size_t)b * LPIX;
  const float* q1 = q0 + 16384;
  float qv[9];
  float m = -1e30f;
  #pragma unroll
  for (int t = 0; t < 9; ++t) {
    int hh = h + t / 3 - 1, wc = w + t % 3 - 1;
    float v = 0.f;  // zero padding participates in softmax
    if ((unsigned)hh < 32u && (unsigned)wc < 32u) {
      int off = hh * 32 + wc;
      v = (q0[off] + q1[off] + b2) * 0.08838834764831845f;  // 1/sqrt(128)
    }
    qv[t] = v;
    m = fmaxf(m, v);
  }
  float ssum = 0.f;
  #pragma unroll
  for (int t = 0; t < 9; ++t) { qv[t] = expf(qv[t] - m); ssum += qv[t]; }
  const float inv = 1.f / ssum;

  const float* xs = xg + ((size_t)b * CX + CI) * LPIX;
  float um0[9], um1[9];
  float m0 = 0.f, m1 = 0.f, v1a = 0.f, v1b = 0.f, c1 = 0.f;
  #pragma unroll
  for (int t = 0; t < 9; ++t) {
    int hh = h + t / 3 - 1; hh = hh < 0 ? 0 : (hh > 31 ? 31 : hh);  // edge pad
    int wc = w + t % 3 - 1; wc = wc < 0 ? 0 : (wc > 31 ? 31 : wc);
    int off = hh * 32 + wc;
    float quv = qv[t] * inv;
    qv[t] = quv;
    float a0 = xs[off];
    float a1 = xs[LPIX + off];
    float b0 = xs[2 * LPIX + off];
    float b1 = xs[3 * LPIX + off];
    float cc = xs[4 * LPIX + off];
    um0[t] = a0; um1[t] = a1;
    m0 = fmaf(a0, quv, m0);
    m1 = fmaf(a1, quv, m1);
    v1a = fmaf(b0, quv, v1a);
    v1b = fmaf(b1, quv, v1b);
    c1 = fmaf(cc, quv, c1);
  }
  float var0 = v1a, var1 = v1b, cov = c1;
  #pragma unroll
  for (int t = 0; t < 9; ++t) {
    float d0 = um0[t] - m0, d1 = um1[t] - m1;
    var0 = fmaf(d0 * d0, qv[t], var0);
    var1 = fmaf(d1 * d1, qv[t], var1);
    cov  = fmaf(d0 * d1, qv[t], cov);
  }
  float* ob = outg + ((size_t)b * 133 + 128) * LPIX + h * 32 + w;
  ob[0 * LPIX] = m0;
  ob[1 * LPIX] = m1;
  ob[2 * LPIX] = var0;
  ob[3 * LPIX] = var1;
  ob[4 * LPIX] = cov;
}

extern "C" void kernel_launch(void* const* d_in, const int* in_sizes, int n_in,
                              void* d_out, int out_size, void* d_ws, size_t ws_size,
                              hipStream_t stream) {
  const float* x  = (const float*)d_in[0];
  const float* cw = (const float*)d_in[1];
  const float* cb = (const float*)d_in[2];
  const float* w2 = (const float*)d_in[3];
  const float* b2 = (const float*)d_in[4];
  const float* sk = (const float*)d_in[5];
  float* out = (float*)d_out;
  float* ws  = (float*)d_ws;   // needs (32768+73728+5760)*4 = ~440 KB

  prep<<<dim3(311), dim3(256), 0, stream>>>(cw, sk, ws);
  convA<<<dim3(512), dim3(512), 0, stream>>>(x, cb, w2, ws, out);
  statsB<<<dim3(256), dim3(64), 0, stream>>>(x, ws, b2, out);
}